// Round 1
// 203.470 us; speedup vs baseline: 1.0110x; 1.0110x over previous
//
#include <hip/hip_runtime.h>
#include <hip/hip_bf16.h>
#include <math.h>

// B=4, N=4096, F=512, C=64. M = B*N = 16384 rows.
#define M_ROWS 16384
#define F_DIM 512
#define C_DIM 64

typedef short bf16x8 __attribute__((ext_vector_type(8)));
typedef float floatx4 __attribute__((ext_vector_type(4)));
typedef unsigned short ushortx8 __attribute__((ext_vector_type(8)));
typedef unsigned short ushortx4 __attribute__((ext_vector_type(4)));

static __device__ __forceinline__ unsigned short f2bf(float x) {
    __hip_bfloat16 h = __float2bfloat16(x);   // RN
    return *reinterpret_cast<unsigned short*>(&h);
}
static __device__ __forceinline__ float bf2f(unsigned short h) {
    unsigned int u = ((unsigned int)h) << 16;
    return __builtin_bit_cast(float, u);
}

// LDS-only barrier: global loads stay in flight (no vmcnt(0) drain).
static __device__ __forceinline__ void lgkm_barrier() {
    asm volatile("s_waitcnt lgkmcnt(0)\n\ts_barrier" ::: "memory");
}

// ---------------------------------------------------------------------------
// Frag-linear layouts (MFMA B-operand order): element (n,k) of a 16-col group
// lives at lane=(k>>3&3)*16+(n&15), j=k&7 -> [group][lane][8] contiguous.
//   wt    : group = (c>>4)*16 + (k>>5)            (640 cols x 512 k)
//   h_sw  : [b][mtile(64)][group=(Fcol>>4)*2+(mloc>>5)][lane][8]
// ---------------------------------------------------------------------------

// Kernel 0: weight transpose + bf16 hi/lo split -> frag-linear.
__global__ __launch_bounds__(64) void prep_w_kernel(
    const float* __restrict__ Wf, const float* __restrict__ Wg,
    const float* __restrict__ Wh,
    unsigned short* __restrict__ wt_hi, unsigned short* __restrict__ wt_lo)
{
    const int c = blockIdx.x;
    const int t = threadIdx.x;
    const float* W; int ld, cl;
    if (c < 64)       { W = Wf; ld = C_DIM; cl = c; }
    else if (c < 128) { W = Wg; ld = C_DIM; cl = c - 64; }
    else              { W = Wh; ld = F_DIM; cl = c - 128; }
    const int ng = c >> 4, l16 = c & 15;
    for (int k = t; k < F_DIM; k += 64) {
        const float x = W[(size_t)k * ld + cl];
        const unsigned short h = f2bf(x);
        const int kh = k >> 5, qd = (k >> 3) & 3, j = k & 7;
        const size_t off = (((size_t)(ng * 16 + kh) * 64) + qd * 16 + l16) * 8 + j;
        wt_hi[off] = h;
        wt_lo[off] = f2bf(x - bf2f(h));
    }
}

// ---------------------------------------------------------------------------
// Kernel 1: MFMA embed GEMM, 64 rows x 128 cols per block. blockIdx.y:
// 0 -> f|g fused (hi/lo 3-MFMA path), 1..4 -> h cols (y-1)*128 (plain bf16).
// Wave w owns cols w*32..+32. B frags straight from global frag-linear wt.
// ---------------------------------------------------------------------------
#define BM 64
#define LDK 72

__global__ __launch_bounds__(256, 4) void embed_mfma_kernel(
    const float* __restrict__ V,
    const unsigned short* __restrict__ wt_hi, const unsigned short* __restrict__ wt_lo,
    const float* __restrict__ bf, const float* __restrict__ bg,
    const float* __restrict__ bh,
    unsigned short* __restrict__ f_bf, unsigned short* __restrict__ g_bf,
    unsigned short* __restrict__ h_sw)
{
    __shared__ __align__(16) unsigned short a_hi[BM][LDK];
    __shared__ __align__(16) unsigned short a_lo[BM][LDK];

    const int t  = threadIdx.x;
    const int R0 = blockIdx.x * BM;
    const bool fg = (blockIdx.y == 0);
    const int cbase = fg ? 0 : blockIdx.y * 128;   // wt col base (g at 64, h at 128+)

    const int w = t >> 6, lane = t & 63, quad = lane >> 4, l16 = lane & 15;

    floatx4 acc[4][2];
    #pragma unroll
    for (int rt = 0; rt < 4; ++rt)
        #pragma unroll
        for (int c = 0; c < 2; ++c)
            acc[rt][c] = (floatx4){0.f, 0.f, 0.f, 0.f};

    const int arow = t >> 4;          // 0..15 (+16/round)
    const int acol = (t & 15) * 4;    // float index (16 B chunks)
    const int ng0  = (cbase >> 4) + w * 2;

    #pragma unroll 1
    for (int k0 = 0; k0 < F_DIM; k0 += 64) {
        lgkm_barrier();   // protect previous iteration's a-frag reads
        // ---- stage A: V fp32 -> bf16 hi/lo in LDS ----
        #pragma unroll
        for (int rr = 0; rr < 4; ++rr) {
            const int row = rr * 16 + arow;
            const float4 x = *(const float4*)(V + (size_t)(R0 + row) * F_DIM + k0 + acol);
            const float xs[4] = {x.x, x.y, x.z, x.w};
            ushortx4 hi, lo;
            #pragma unroll
            for (int jj = 0; jj < 4; ++jj) {
                const unsigned short hb2 = f2bf(xs[jj]);
                hi[jj] = hb2;
                lo[jj] = f2bf(xs[jj] - bf2f(hb2));
            }
            *(ushortx4*)&a_hi[row][acol] = hi;
            if (fg) *(ushortx4*)&a_lo[row][acol] = lo;
        }
        lgkm_barrier();
        // ---- compute ----
        #pragma unroll
        for (int kk = 0; kk < 2; ++kk) {
            const int kh = (k0 >> 5) + kk;
            const bf16x8 b0 = *(const bf16x8*)(wt_hi + (((size_t)(ng0 * 16 + kh)) * 64 + lane) * 8);
            const bf16x8 b1 = *(const bf16x8*)(wt_hi + (((size_t)((ng0 + 1) * 16 + kh)) * 64 + lane) * 8);
            bf16x8 ah[4];
            #pragma unroll
            for (int rt = 0; rt < 4; ++rt)
                ah[rt] = *(const bf16x8*)&a_hi[rt * 16 + l16][kk * 32 + quad * 8];
            #pragma unroll
            for (int rt = 0; rt < 4; ++rt) {
                acc[rt][0] = __builtin_amdgcn_mfma_f32_16x16x32_bf16(ah[rt], b0, acc[rt][0], 0, 0, 0);
                acc[rt][1] = __builtin_amdgcn_mfma_f32_16x16x32_bf16(ah[rt], b1, acc[rt][1], 0, 0, 0);
            }
            if (fg) {
                const bf16x8 c0 = *(const bf16x8*)(wt_lo + (((size_t)(ng0 * 16 + kh)) * 64 + lane) * 8);
                const bf16x8 c1 = *(const bf16x8*)(wt_lo + (((size_t)((ng0 + 1) * 16 + kh)) * 64 + lane) * 8);
                bf16x8 al[4];
                #pragma unroll
                for (int rt = 0; rt < 4; ++rt)
                    al[rt] = *(const bf16x8*)&a_lo[rt * 16 + l16][kk * 32 + quad * 8];
                #pragma unroll
                for (int rt = 0; rt < 4; ++rt) {
                    acc[rt][0] = __builtin_amdgcn_mfma_f32_16x16x32_bf16(ah[rt], c0, acc[rt][0], 0, 0, 0);
                    acc[rt][0] = __builtin_amdgcn_mfma_f32_16x16x32_bf16(al[rt], b0, acc[rt][0], 0, 0, 0);
                    acc[rt][1] = __builtin_amdgcn_mfma_f32_16x16x32_bf16(ah[rt], c1, acc[rt][1], 0, 0, 0);
                    acc[rt][1] = __builtin_amdgcn_mfma_f32_16x16x32_bf16(al[rt], b1, acc[rt][1], 0, 0, 0);
                }
            }
        }
    }

    // ---- epilogue: bias + relu + bf16, route by wt column ----
    #pragma unroll
    for (int rt = 0; rt < 4; ++rt) {
        #pragma unroll
        for (int c = 0; c < 2; ++c) {
            const int wtc  = cbase + w * 32 + c * 16 + l16;   // 0..639
            const int rowl = rt * 16 + quad * 4;
            const float bias = fg ? (wtc < 64 ? bf[wtc] : bg[wtc - 64]) : bh[wtc - 128];
            const floatx4 v = acc[rt][c];
            if (fg) {
                unsigned short* dst = (wtc < 64) ? (f_bf + wtc) : (g_bf + wtc - 64);
                #pragma unroll
                for (int r = 0; r < 4; ++r) {
                    const float z = v[r] + bias;
                    dst[(size_t)(R0 + rowl + r) * C_DIM] = f2bf(z > 0.f ? z : 0.f);
                }
            } else {
                const int hc   = wtc - 128;                   // global F col
                const int grow = R0 + rowl;
                const int b    = grow >> 12, rl = grow & 4095;
                const int T    = rl >> 6, mloc = rl & 63;
                const int kh2  = mloc >> 5, q2 = (mloc >> 3) & 3, j0 = mloc & 7;
                ushortx4 st;
                #pragma unroll
                for (int r = 0; r < 4; ++r) {
                    const float z = v[r] + bias;
                    st[r] = f2bf(z > 0.f ? z : 0.f);
                }
                const size_t off = ((((size_t)(b * 64 + T) * 64) + (hc >> 4) * 2 + kh2) * 64
                                    + q2 * 16 + (hc & 15)) * 8 + j0;
                *(ushortx4*)(h_sw + off) = st;
            }
        }
    }
}

// ---------------------------------------------------------------------------
// Kernel 2: MFMA attention, FULLY FUSED (no m-split, no reduce pass).
// QT=64 q-rows per block, grid = 4 batches x 64 q-tiles = 256 blocks.
// Each block sees ALL 4096 keys -> complete softmax row-sum in-block; the
// epilogue applies gamma*O/l + V in fp32 directly (no O_ws bf16 roundtrip).
//
// LDS tiles are exact 128 B stride with T2 XOR-swizzle (byte ^= (row&7)<<4):
// every ds_read_b128 fragment read puts exactly 8 lanes on each 16 B slot
// group -> conflict-free (was ~20% of cycles in SQ_LDS_BANK_CONFLICT with
// the old +8-short padding).
//
// Score partition: wave w -> rows (w&3)*16, cols (w>>2)*16 of the 64x64
// score tile. PV partition: wave w owns ALL 64 rows x 32 F-cols [w*32,+32);
// its 4 h frags (groups 4w..4w+3) are one contiguous 4 KB block, so the 16
// waves tile the 64 KB h mtile exactly once. Barriers lgkm-only.
// ---------------------------------------------------------------------------
#define QT 64
#define KT 64

__global__ __launch_bounds__(1024, 4) void attn_mfma_kernel(
    const unsigned short* __restrict__ f_bf, const unsigned short* __restrict__ g_bf,
    const unsigned short* __restrict__ h_sw, const float* __restrict__ gamma,
    const float* __restrict__ V, float* __restrict__ out)
{
    __shared__ __align__(16) unsigned short p_lds[2][QT * 64];   // 16 KB, swizzled
    __shared__ __align__(16) unsigned short g_lds[2][KT * 64];   // 16 KB, swizzled
    __shared__ float l_red[4][QT];                               // 1 KB
    __shared__ float l_inv[QT];

    const int t = threadIdx.x;
    const int w = t >> 6, lane = t & 63, quad = lane >> 4, l16 = lane & 15;
    const int wr = w & 3, wc = w >> 2;     // score stripe: rows wr*16, cols wc*16

    // XCD-chunked mapping: XCD x (=bid&7) gets 32 consecutive q-tiles of one
    // batch -> per-XCD L2 streams one batch's h/g in lockstep.
    const int bid  = blockIdx.x;
    const int orig = (bid & 7) * 32 + (bid >> 3);
    const int b    = orig >> 6, qb = orig & 63;
    const int R0   = qb * QT;

    const unsigned short* fb    = f_bf + ((size_t)b * 4096 + R0) * C_DIM;
    const unsigned short* gb    = g_bf + (size_t)b * 4096 * C_DIM;
    const unsigned short* hbase = h_sw + (size_t)b * 64 * 32768;

    bf16x8 f0, f1;
    {
        const unsigned short* fr = fb + (size_t)(wr * 16 + l16) * C_DIM + quad * 8;
        f0 = *(const bf16x8*)fr;
        f1 = *(const bf16x8*)(fr + 32);
    }
    const float gam0 = gamma[w * 32 + l16];
    const float gam1 = gamma[w * 32 + 16 + l16];

    floatx4 acc[4][2];   // [row-tile][col-16-group]; cols w*32 + c*16
    #pragma unroll
    for (int rt = 0; rt < 4; ++rt)
        #pragma unroll
        for (int c = 0; c < 2; ++c)
            acc[rt][c] = (floatx4){0.f, 0.f, 0.f, 0.f};
    float run_l[4] = {0.f, 0.f, 0.f, 0.f};

    // cooperative g stage: thread t -> (row=t>>4, 8 B chunk), swizzled dest
    const int grow    = t >> 4, gk = (t & 15) * 4;
    const int g_swoff = grow * 128 + ((gk * 2) ^ ((grow & 7) << 4));
    ushortx4 greg = *(const ushortx4*)(gb + (size_t)grow * C_DIM + gk);

    // loop-invariant swizzled read offsets
    const int sgrow   = wc * 16 + l16;                      // g row for scores
    const int sg_off0 = sgrow * 128 + ((quad * 16)      ^ ((sgrow & 7) << 4));
    const int sg_off1 = sgrow * 128 + ((quad * 16 + 64) ^ ((sgrow & 7) << 4));

    for (int it = 0; it < 64; ++it) {
        const int buf = it & 1;
        const unsigned short* ht = hbase + (size_t)it * 32768 + (size_t)(4 * w) * 512;

        // ---- h prefetch: this wave's contiguous 4 KB (groups 4w..4w+3) ----
        const bf16x8 h0 = *(const bf16x8*)(ht + (size_t)lane * 8);
        const bf16x8 h1 = *(const bf16x8*)(ht + 512 + (size_t)lane * 8);
        const bf16x8 h2 = *(const bf16x8*)(ht + 1024 + (size_t)lane * 8);
        const bf16x8 h3 = *(const bf16x8*)(ht + 1536 + (size_t)lane * 8);

        *(ushortx4*)((unsigned char*)&g_lds[buf][0] + g_swoff) = greg;
        if (it < 63)
            greg = *(const ushortx4*)(gb + (size_t)((it + 1) * KT + grow) * C_DIM + gk);
        lgkm_barrier();   // g[buf] visible

        const unsigned char* gB = (const unsigned char*)&g_lds[buf][0];
        unsigned char*       pB = (unsigned char*)&p_lds[buf][0];

        // ---- scores stripe: rows wr*16..+16, cols wc*16..+16 ----
        {
            const bf16x8 g0 = *(const bf16x8*)(gB + sg_off0);
            const bf16x8 g1 = *(const bf16x8*)(gB + sg_off1);
            floatx4 cc = (floatx4){0.f, 0.f, 0.f, 0.f};
            cc = __builtin_amdgcn_mfma_f32_16x16x32_bf16(f0, g0, cc, 0, 0, 0);
            cc = __builtin_amdgcn_mfma_f32_16x16x32_bf16(f1, g1, cc, 0, 0, 0);
            #pragma unroll
            for (int r = 0; r < 4; ++r) {
                const float p = __expf(cc[r] - 32.f);
                run_l[r] += p;
                const int prow = wr * 16 + quad * 4 + r;
                const int pcol = wc * 16 + l16;
                *(unsigned short*)(pB + prow * 128 + ((pcol * 2) ^ ((prow & 7) << 4))) = f2bf(p);
            }
        }
        lgkm_barrier();   // p[buf] visible

        // ---- PV: all 64 rows x this wave's 32 cols ----
        #pragma unroll
        for (int rt = 0; rt < 4; ++rt) {
            const int prow = rt * 16 + l16;
            const int sw   = (prow & 7) << 4;
            const bf16x8 pf0 = *(const bf16x8*)(pB + prow * 128 + ((quad * 16)      ^ sw));
            const bf16x8 pf1 = *(const bf16x8*)(pB + prow * 128 + ((quad * 16 + 64) ^ sw));
            acc[rt][0] = __builtin_amdgcn_mfma_f32_16x16x32_bf16(pf0, h0, acc[rt][0], 0, 0, 0);
            acc[rt][0] = __builtin_amdgcn_mfma_f32_16x16x32_bf16(pf1, h1, acc[rt][0], 0, 0, 0);
            acc[rt][1] = __builtin_amdgcn_mfma_f32_16x16x32_bf16(pf0, h2, acc[rt][1], 0, 0, 0);
            acc[rt][1] = __builtin_amdgcn_mfma_f32_16x16x32_bf16(pf1, h3, acc[rt][1], 0, 0, 0);
        }
    }

    // ---- full row-sum l: shfl over l16, then LDS-sum across the 4 wc ----
    #pragma unroll
    for (int r = 0; r < 4; ++r) {
        float v = run_l[r];
        v += __shfl_xor(v, 1, 64);
        v += __shfl_xor(v, 2, 64);
        v += __shfl_xor(v, 4, 64);
        v += __shfl_xor(v, 8, 64);
        if (l16 == 0) l_red[wc][wr * 16 + quad * 4 + r] = v;
    }
    __syncthreads();
    if (t < QT)
        l_inv[t] = 1.f / (l_red[0][t] + l_red[1][t] + l_red[2][t] + l_red[3][t]);
    __syncthreads();

    // ---- fused epilogue: out = gamma * O/l + V (fp32, final) ----
    const float* Vb = V   + ((size_t)b * 4096 + R0) * F_DIM;
    float*       ob = out + ((size_t)b * 4096 + R0) * F_DIM;
    const int c0 = w * 32 + l16;
    #pragma unroll
    for (int rt = 0; rt < 4; ++rt) {
        #pragma unroll
        for (int r = 0; r < 4; ++r) {
            const int row = rt * 16 + quad * 4 + r;
            const float li = l_inv[row];
            ob[(size_t)row * F_DIM + c0]      = gam0 * acc[rt][0][r] * li + Vb[(size_t)row * F_DIM + c0];
            ob[(size_t)row * F_DIM + c0 + 16] = gam1 * acc[rt][1][r] * li + Vb[(size_t)row * F_DIM + c0 + 16];
        }
    }
}

// ---------------------------------------------------------------------------
extern "C" void kernel_launch(void* const* d_in, const int* in_sizes, int n_in,
                              void* d_out, int out_size, void* d_ws, size_t ws_size,
                              hipStream_t stream) {
    const float* V     = (const float*)d_in[0];
    const float* Wf    = (const float*)d_in[1];
    const float* bf    = (const float*)d_in[2];
    const float* Wg    = (const float*)d_in[3];
    const float* bg    = (const float*)d_in[4];
    const float* Wh    = (const float*)d_in[5];
    const float* bh    = (const float*)d_in[6];
    const float* gamma = (const float*)d_in[7];
    float* out = (float*)d_out;

    // ws: f 2MB | g 2MB | h_sw 16MB | wt_hi 0.64 | wt_lo 0.64
    unsigned short* f_bf  = (unsigned short*)d_ws;
    unsigned short* g_bf  = f_bf + (size_t)M_ROWS * C_DIM;
    unsigned short* h_sw  = g_bf + (size_t)M_ROWS * C_DIM;
    unsigned short* wt_hi = h_sw + (size_t)4 * F_DIM * 4096;
    unsigned short* wt_lo = wt_hi + (size_t)640 * F_DIM;

    prep_w_kernel<<<640, 64, 0, stream>>>(Wf, Wg, Wh, wt_hi, wt_lo);
    embed_mfma_kernel<<<dim3(M_ROWS / BM, 5), 256, 0, stream>>>(
        V, wt_hi, wt_lo, bf, bg, bh, f_bf, g_bf, h_sw);
    attn_mfma_kernel<<<256, 1024, 0, stream>>>(f_bf, g_bf, h_sw, gamma, V, out);
}